// Round 1
// baseline (509.459 us; speedup 1.0000x reference)
//
#include <hip/hip_runtime.h>
#include <hip/hip_bf16.h>
#include <math.h>

// Problem dims (fixed by the reference)
#define PB 8
#define PS 4096
#define PD 1024

typedef __attribute__((ext_vector_type(8))) short bf16x8;
typedef __attribute__((ext_vector_type(4))) float f32x4;

__device__ __forceinline__ ushort f2b(float f) {
    // round-to-nearest-even f32 -> bf16
    unsigned u = __float_as_uint(f);
    unsigned r = (u + 0x7FFFu + ((u >> 16) & 1u)) >> 16;
    return (ushort)r;
}
__device__ __forceinline__ float b2f(ushort h) {
    return __uint_as_float(((unsigned)h) << 16);
}

__device__ __forceinline__ void gl2lds16(const void* g, void* l) {
    // async global->LDS, 16B/lane; LDS dest is wave-uniform base + lane*16
    __builtin_amdgcn_global_load_lds(
        (const __attribute__((address_space(1))) void*)g,
        (__attribute__((address_space(3))) void*)l, 16, 0, 0);
}

__global__ __launch_bounds__(256) void cvt_f32_bf16(const float* __restrict__ in,
                                                    ushort* __restrict__ out, int n) {
    int i = (blockIdx.x * 256 + threadIdx.x) * 4;
    if (i + 3 < n) {
        float4 v = *(const float4*)(in + i);
        ushort4 o;
        o.x = f2b(v.x); o.y = f2b(v.y); o.z = f2b(v.z); o.w = f2b(v.w);
        *(ushort4*)(out + i) = o;
    }
}

// C = A (MxK, row-major bf16) * Bm^T (Bm is NxK row-major bf16) + bias
// 128x128 block tile, BK=32, 256 threads = 4 waves, each wave 64x64 (4x4 MFMA tiles)
template <bool OUT_BF16>
__global__ __launch_bounds__(256) void gemm_bt(const ushort* __restrict__ A,
                                               const ushort* __restrict__ Bm,
                                               const float* __restrict__ bias,
                                               void* __restrict__ C,
                                               int M, int N, int K) {
    __shared__ ushort As[128 * 32];   // 8 KB, unpadded (required by global_load_lds)
    __shared__ ushort Bs[128 * 32];

    const int tid = threadIdx.x;
    const int lane = tid & 63;
    const int wave = tid >> 6;
    const int nbn = N >> 7;
    const int bn = blockIdx.x % nbn;
    const int bm = blockIdx.x / nbn;
    const int wm = wave >> 1, wn = wave & 1;
    const int l15 = lane & 15, quad = lane >> 4;

    // staging: element offset in 128x32 tile; wave w stages elements [w*512, w*512+512) and +2048
    const int e0 = wave * 512 + lane * 8;
    const int sr = e0 >> 5;          // 0..63
    const int sc = e0 & 31;
    const ushort* Ag = A + (size_t)(bm * 128 + sr) * K + sc;
    const ushort* Bg = Bm + (size_t)(bn * 128 + sr) * K + sc;
    ushort* Asw = As + wave * 512;   // wave-uniform LDS base (bytes: wave*1024)
    ushort* Bsw = Bs + wave * 512;

    f32x4 acc[4][4];
#pragma unroll
    for (int i = 0; i < 4; ++i)
#pragma unroll
        for (int j = 0; j < 4; ++j) acc[i][j] = (f32x4){0.f, 0.f, 0.f, 0.f};

    for (int k0 = 0; k0 < K; k0 += 32) {
        __syncthreads();
        gl2lds16(Ag + k0, Asw);
        gl2lds16(Ag + k0 + (size_t)64 * K, Asw + 2048);
        gl2lds16(Bg + k0, Bsw);
        gl2lds16(Bg + k0 + (size_t)64 * K, Bsw + 2048);
        __syncthreads();

        bf16x8 af[4], bfr[4];
#pragma unroll
        for (int i = 0; i < 4; ++i)
            af[i] = *(const bf16x8*)(As + (wm * 64 + i * 16 + l15) * 32 + quad * 8);
#pragma unroll
        for (int j = 0; j < 4; ++j)
            bfr[j] = *(const bf16x8*)(Bs + (wn * 64 + j * 16 + l15) * 32 + quad * 8);
#pragma unroll
        for (int i = 0; i < 4; ++i)
#pragma unroll
            for (int j = 0; j < 4; ++j)
                acc[i][j] = __builtin_amdgcn_mfma_f32_16x16x32_bf16(af[i], bfr[j], acc[i][j], 0, 0, 0);
    }

    // epilogue: C/D layout col=lane&15, row=quad*4+reg  [verified m89/m91]
    const int gm0 = bm * 128 + wm * 64;
    const int gn0 = bn * 128 + wn * 64;
    float bv[4];
#pragma unroll
    for (int j = 0; j < 4; ++j) bv[j] = bias[gn0 + j * 16 + l15];
#pragma unroll
    for (int i = 0; i < 4; ++i) {
#pragma unroll
        for (int j = 0; j < 4; ++j) {
            const int col = gn0 + j * 16 + l15;
#pragma unroll
            for (int r = 0; r < 4; ++r) {
                const int row = gm0 + i * 16 + quad * 4 + r;
                float v = acc[i][j][r] + bv[j];
                if (OUT_BF16)
                    ((ushort*)C)[(size_t)row * N + col] = f2b(v);
                else
                    ((float*)C)[(size_t)row * N + col] = v;
            }
        }
    }
}

// Pass A: per (b, chunk) compute affine (A_c scalar, B_c vector of D)
__global__ __launch_bounds__(256) void scan_partial(const ushort* __restrict__ upd,
                                                    const float* __restrict__ mask,
                                                    const float* __restrict__ dp,
                                                    float* __restrict__ Bc,
                                                    float* __restrict__ Ac,
                                                    int S, int D, int C) {
    const int c = blockIdx.x % C;
    const int b = blockIdx.x / C;
    const int L = S / C;
    const int d0 = threadIdx.x * 4;
    const float decay = 1.f / (1.f + expf(-dp[0]));
    const ushort* up = upd + ((size_t)b * S + (size_t)c * L) * D + d0;
    const float* mp = mask + (size_t)b * S + (size_t)c * L;
    float aA = 1.f;
    float b0 = 0.f, b1 = 0.f, b2 = 0.f, b3 = 0.f;
    for (int s = 0; s < L; ++s) {
        float m = mp[s];
        float a = m * decay + (1.f - m);
        ushort4 u = *(const ushort4*)(up + (size_t)s * D);
        aA *= a;
        b0 = a * b0 + m * b2f(u.x);
        b1 = a * b1 + m * b2f(u.y);
        b2 = a * b2 + m * b2f(u.z);
        b3 = a * b3 + m * b2f(u.w);
    }
    *(float4*)(Bc + (size_t)blockIdx.x * D + d0) = make_float4(b0, b1, b2, b3);
    if (threadIdx.x == 0) Ac[blockIdx.x] = aA;
}

// Pass B: serial prefix over C chunks per (b,d) chain; writes incoming state per chunk
__global__ __launch_bounds__(256) void scan_prefix(const float* __restrict__ Ac,
                                                   const float* __restrict__ Bc,
                                                   float* __restrict__ Mn, int D, int C) {
    int gid = blockIdx.x * 256 + threadIdx.x;  // over B*D
    int b = gid / D;
    int d = gid - b * D;
    float mem = 0.f;
    for (int c = 0; c < C; ++c) {
        size_t idx = ((size_t)(b * C + c)) * D + d;
        Mn[idx] = mem;
        mem = Ac[b * C + c] * mem + Bc[idx];
    }
}

// Pass C: replay each chunk from its incoming state, write mem_seq (bf16)
__global__ __launch_bounds__(256) void scan_final(const ushort* __restrict__ upd,
                                                  const float* __restrict__ mask,
                                                  const float* __restrict__ dp,
                                                  const float* __restrict__ Mn,
                                                  ushort* __restrict__ ms,
                                                  int S, int D, int C) {
    const int c = blockIdx.x % C;
    const int b = blockIdx.x / C;
    const int L = S / C;
    const int d0 = threadIdx.x * 4;
    const float decay = 1.f / (1.f + expf(-dp[0]));
    const ushort* up = upd + ((size_t)b * S + (size_t)c * L) * D + d0;
    ushort* op = ms + ((size_t)b * S + (size_t)c * L) * D + d0;
    const float* mp = mask + (size_t)b * S + (size_t)c * L;
    float4 m0 = *(const float4*)(Mn + (size_t)blockIdx.x * D + d0);
    float v0 = m0.x, v1 = m0.y, v2 = m0.z, v3 = m0.w;
    for (int s = 0; s < L; ++s) {
        float m = mp[s];
        float a = m * decay + (1.f - m);
        ushort4 u = *(const ushort4*)(up + (size_t)s * D);
        v0 = a * v0 + m * b2f(u.x);
        v1 = a * v1 + m * b2f(u.y);
        v2 = a * v2 + m * b2f(u.z);
        v3 = a * v3 + m * b2f(u.w);
        ushort4 o;
        o.x = f2b(v0); o.y = f2b(v1); o.z = f2b(v2); o.w = f2b(v3);
        *(ushort4*)(op + (size_t)s * D) = o;
    }
}

extern "C" void kernel_launch(void* const* d_in, const int* in_sizes, int n_in,
                              void* d_out, int out_size, void* d_ws, size_t ws_size,
                              hipStream_t stream) {
    const float* x    = (const float*)d_in[0];
    const float* mask = (const float*)d_in[1];
    const float* Wu   = (const float*)d_in[2];
    const float* bu   = (const float*)d_in[3];
    const float* Wf   = (const float*)d_in[4];
    const float* bfv  = (const float*)d_in[5];
    const float* dp   = (const float*)d_in[6];

    const int B = PB, S = PS, D = PD;
    const int M = B * S;          // 32768
    const int C = 128;            // scan chunks; L = 32

    // workspace layout (bytes): total ~204 MB
    char* ws = (char*)d_ws;
    ushort* xb   = (ushort*)(ws);                 // 64 MB  bf16 x
    ushort* updb = (ushort*)(ws + 67108864);      // 64 MB  bf16 upd
    ushort* memb = (ushort*)(ws + 134217728);     // 64 MB  bf16 mem_seq
    ushort* Wub  = (ushort*)(ws + 201326592);     // 2 MB
    ushort* Wfb  = (ushort*)(ws + 203423744);     // 2 MB
    float*  Bc   = (float*)(ws + 205520896);      // 4 MB   B*C*D
    float*  Mn   = (float*)(ws + 209715200);      // 4 MB   B*C*D
    float*  Ac   = (float*)(ws + 213909504);      // 4 KB   B*C

    const int nx = B * S * D;
    cvt_f32_bf16<<<nx / 1024, 256, 0, stream>>>(x, xb, nx);
    cvt_f32_bf16<<<(D * D) / 1024, 256, 0, stream>>>(Wu, Wub, D * D);
    cvt_f32_bf16<<<(D * D) / 1024, 256, 0, stream>>>(Wf, Wfb, D * D);

    dim3 g1((M / 128) * (D / 128));  // 2048 blocks
    gemm_bt<true><<<g1, 256, 0, stream>>>(xb, Wub, bu, (void*)updb, M, D, D);

    scan_partial<<<B * C, 256, 0, stream>>>(updb, mask, dp, Bc, Ac, S, D, C);
    scan_prefix<<<(B * D) / 256, 256, 0, stream>>>(Ac, Bc, Mn, D, C);
    scan_final<<<B * C, 256, 0, stream>>>(updb, mask, dp, Mn, memb, S, D, C);

    gemm_bt<false><<<g1, 256, 0, stream>>>(memb, Wfb, bfv, d_out, M, D, D);
}

// Round 2
// 482.025 us; speedup vs baseline: 1.0569x; 1.0569x over previous
//
#include <hip/hip_runtime.h>
#include <hip/hip_bf16.h>
#include <math.h>

// Problem dims (fixed by the reference)
#define PB 8
#define PS 4096
#define PD 1024

typedef __attribute__((ext_vector_type(8))) short bf16x8;
typedef __attribute__((ext_vector_type(4))) float f32x4;

__device__ __forceinline__ ushort f2b(float f) {
    // round-to-nearest-even f32 -> bf16
    unsigned u = __float_as_uint(f);
    unsigned r = (u + 0x7FFFu + ((u >> 16) & 1u)) >> 16;
    return (ushort)r;
}
__device__ __forceinline__ float b2f(ushort h) {
    return __uint_as_float(((unsigned)h) << 16);
}

__device__ __forceinline__ void gl2lds16(const void* g, void* l) {
    // async global->LDS, 16B/lane; LDS dest is wave-uniform base + lane*16
    __builtin_amdgcn_global_load_lds(
        (const __attribute__((address_space(1))) void*)g,
        (__attribute__((address_space(3))) void*)l, 16, 0, 0);
}

__global__ __launch_bounds__(256) void cvt_f32_bf16(const float* __restrict__ in,
                                                    ushort* __restrict__ out, int n) {
    int i = (blockIdx.x * 256 + threadIdx.x) * 4;
    if (i + 3 < n) {
        float4 v = *(const float4*)(in + i);
        ushort4 o;
        o.x = f2b(v.x); o.y = f2b(v.y); o.z = f2b(v.z); o.w = f2b(v.w);
        *(ushort4*)(out + i) = o;
    }
}

// both weight matrices in one dispatch
__global__ __launch_bounds__(256) void cvt_w2(const float* __restrict__ Wu,
                                              const float* __restrict__ Wf,
                                              ushort* __restrict__ Wub,
                                              ushort* __restrict__ Wfb, int n) {
    int i = (blockIdx.x * 256 + threadIdx.x) * 4;
    const float* in = (i < n) ? Wu : Wf;
    ushort* out = (i < n) ? Wub : Wfb;
    int j = (i < n) ? i : i - n;
    float4 v = *(const float4*)(in + j);
    ushort4 o;
    o.x = f2b(v.x); o.y = f2b(v.y); o.z = f2b(v.z); o.w = f2b(v.w);
    *(ushort4*)(out + j) = o;
}

// C = A (MxK, row-major bf16) * Bm^T (Bm is NxK row-major bf16) + bias
// 128x128 block tile, BK=32, 256 threads = 4 waves, each wave 64x64 (4x4 MFMA tiles)
// LDS layout XOR-swizzled: slot granule g of row r holds logical granule g^((r>>1)&3)
// (granule = 16B = 8 bf16). Swizzle applied on the GLOBAL address side of the DMA.
template <bool OUT_BF16>
__global__ __launch_bounds__(256) void gemm_bt(const ushort* __restrict__ A,
                                               const ushort* __restrict__ Bm,
                                               const float* __restrict__ bias,
                                               void* __restrict__ C,
                                               int M, int N, int K) {
    __shared__ ushort As[128 * 32];   // 8 KB, unpadded (required by global_load_lds)
    __shared__ ushort Bs[128 * 32];

    const int tid = threadIdx.x;
    const int lane = tid & 63;
    const int wave = tid >> 6;
    const int nbn = N >> 7;                    // 8
    // XCD-aware mapping: XCD = blockIdx % 8 (dispatch heuristic). Each XCD owns
    // nbm/8 consecutive bm values; within an XCD, bn varies fastest -> A tile
    // reused 8 consecutive steps from that XCD's L2. Whole B (2 MB) stays in L2.
    const int xcd = blockIdx.x & 7;
    const int g = blockIdx.x >> 3;
    const int bm = xcd * ((M >> 7) >> 3) + g / nbn;
    const int bn = g % nbn;
    const int wm = wave >> 1, wn = wave & 1;
    const int l15 = lane & 15, quad = lane >> 4;

    // staging: wave stages rows [wave*16, wave*16+16) and +64, 16 rows x 32 cols.
    // LDS slot for this lane: row = wave*16 + (lane>>2) (+64), granule = lane&3.
    // swizzle: fetch logical granule (lane&3) ^ ((lane>>3)&3) from global.
    const int grow = wave * 16 + (lane >> 2);
    const int gx = (lane & 3) ^ ((lane >> 3) & 3);
    const ushort* Ag = A + (size_t)(bm * 128 + grow) * K + gx * 8;
    const ushort* Bg = Bm + (size_t)(bn * 128 + grow) * K + gx * 8;
    ushort* Asw = As + wave * 512;   // wave-uniform LDS base
    ushort* Bsw = Bs + wave * 512;

    f32x4 acc[4][4];
#pragma unroll
    for (int i = 0; i < 4; ++i)
#pragma unroll
        for (int j = 0; j < 4; ++j) acc[i][j] = (f32x4){0.f, 0.f, 0.f, 0.f};

    // fragment read: row rr, logical k-granule quad lives at slot granule quad^((rr>>1)&3);
    // rr = (wm|wn)*64 + i*16 + l15 -> (rr>>1)&3 == (l15>>1)&3
    const int rsw = (l15 >> 1) & 3;
    const int aoff = (quad ^ rsw) * 8;

    for (int k0 = 0; k0 < K; k0 += 32) {
        __syncthreads();
        gl2lds16(Ag + k0, Asw);
        gl2lds16(Ag + k0 + (size_t)64 * K, Asw + 2048);
        gl2lds16(Bg + k0, Bsw);
        gl2lds16(Bg + k0 + (size_t)64 * K, Bsw + 2048);
        __syncthreads();

        bf16x8 af[4], bfr[4];
#pragma unroll
        for (int i = 0; i < 4; ++i)
            af[i] = *(const bf16x8*)(As + (wm * 64 + i * 16 + l15) * 32 + aoff);
#pragma unroll
        for (int j = 0; j < 4; ++j)
            bfr[j] = *(const bf16x8*)(Bs + (wn * 64 + j * 16 + l15) * 32 + aoff);
#pragma unroll
        for (int i = 0; i < 4; ++i)
#pragma unroll
            for (int j = 0; j < 4; ++j)
                acc[i][j] = __builtin_amdgcn_mfma_f32_16x16x32_bf16(af[i], bfr[j], acc[i][j], 0, 0, 0);
    }

    // epilogue: C/D layout col=lane&15, row=quad*4+reg  [verified m89/m91]
    const int gm0 = bm * 128 + wm * 64;
    const int gn0 = bn * 128 + wn * 64;
    float bv[4];
#pragma unroll
    for (int j = 0; j < 4; ++j) bv[j] = bias[gn0 + j * 16 + l15];
#pragma unroll
    for (int i = 0; i < 4; ++i) {
#pragma unroll
        for (int j = 0; j < 4; ++j) {
            const int col = gn0 + j * 16 + l15;
#pragma unroll
            for (int r = 0; r < 4; ++r) {
                const int row = gm0 + i * 16 + quad * 4 + r;
                float v = acc[i][j][r] + bv[j];
                if (OUT_BF16)
                    ((ushort*)C)[(size_t)row * N + col] = f2b(v);
                else
                    ((float*)C)[(size_t)row * N + col] = v;
            }
        }
    }
}

// Pass A: per (b, chunk) compute affine (A_c scalar, B_c vector of D)
__global__ __launch_bounds__(256) void scan_partial(const ushort* __restrict__ upd,
                                                    const float* __restrict__ mask,
                                                    const float* __restrict__ dp,
                                                    float* __restrict__ Bc,
                                                    float* __restrict__ Ac,
                                                    int S, int D, int C) {
    const int c = blockIdx.x % C;
    const int b = blockIdx.x / C;
    const int L = S / C;
    const int d0 = threadIdx.x * 4;
    const float decay = 1.f / (1.f + expf(-dp[0]));
    const ushort* up = upd + ((size_t)b * S + (size_t)c * L) * D + d0;
    const float* mp = mask + (size_t)b * S + (size_t)c * L;
    float aA = 1.f;
    float b0 = 0.f, b1 = 0.f, b2 = 0.f, b3 = 0.f;
    for (int s = 0; s < L; ++s) {
        float m = mp[s];
        float a = m * decay + (1.f - m);
        ushort4 u = *(const ushort4*)(up + (size_t)s * D);
        aA *= a;
        b0 = a * b0 + m * b2f(u.x);
        b1 = a * b1 + m * b2f(u.y);
        b2 = a * b2 + m * b2f(u.z);
        b3 = a * b3 + m * b2f(u.w);
    }
    *(float4*)(Bc + (size_t)blockIdx.x * D + d0) = make_float4(b0, b1, b2, b3);
    if (threadIdx.x == 0) Ac[blockIdx.x] = aA;
}

// Pass B: serial prefix over C chunks per (b,d) chain; writes incoming state per chunk
__global__ __launch_bounds__(256) void scan_prefix(const float* __restrict__ Ac,
                                                   const float* __restrict__ Bc,
                                                   float* __restrict__ Mn, int D, int C) {
    int gid = blockIdx.x * 256 + threadIdx.x;  // over B*D
    int b = gid / D;
    int d = gid - b * D;
    float mem = 0.f;
    for (int c = 0; c < C; ++c) {
        size_t idx = ((size_t)(b * C + c)) * D + d;
        Mn[idx] = mem;
        mem = Ac[b * C + c] * mem + Bc[idx];
    }
}

// Pass C: replay each chunk from its incoming state, write mem_seq (bf16)
__global__ __launch_bounds__(256) void scan_final(const ushort* __restrict__ upd,
                                                  const float* __restrict__ mask,
                                                  const float* __restrict__ dp,
                                                  const float* __restrict__ Mn,
                                                  ushort* __restrict__ ms,
                                                  int S, int D, int C) {
    const int c = blockIdx.x % C;
    const int b = blockIdx.x / C;
    const int L = S / C;
    const int d0 = threadIdx.x * 4;
    const float decay = 1.f / (1.f + expf(-dp[0]));
    const ushort* up = upd + ((size_t)b * S + (size_t)c * L) * D + d0;
    ushort* op = ms + ((size_t)b * S + (size_t)c * L) * D + d0;
    const float* mp = mask + (size_t)b * S + (size_t)c * L;
    float4 m0 = *(const float4*)(Mn + (size_t)blockIdx.x * D + d0);
    float v0 = m0.x, v1 = m0.y, v2 = m0.z, v3 = m0.w;
    for (int s = 0; s < L; ++s) {
        float m = mp[s];
        float a = m * decay + (1.f - m);
        ushort4 u = *(const ushort4*)(up + (size_t)s * D);
        v0 = a * v0 + m * b2f(u.x);
        v1 = a * v1 + m * b2f(u.y);
        v2 = a * v2 + m * b2f(u.z);
        v3 = a * v3 + m * b2f(u.w);
        ushort4 o;
        o.x = f2b(v0); o.y = f2b(v1); o.z = f2b(v2); o.w = f2b(v3);
        *(ushort4*)(op + (size_t)s * D) = o;
    }
}

extern "C" void kernel_launch(void* const* d_in, const int* in_sizes, int n_in,
                              void* d_out, int out_size, void* d_ws, size_t ws_size,
                              hipStream_t stream) {
    const float* x    = (const float*)d_in[0];
    const float* mask = (const float*)d_in[1];
    const float* Wu   = (const float*)d_in[2];
    const float* bu   = (const float*)d_in[3];
    const float* Wf   = (const float*)d_in[4];
    const float* bfv  = (const float*)d_in[5];
    const float* dp   = (const float*)d_in[6];

    const int B = PB, S = PS, D = PD;
    const int M = B * S;          // 32768
    const int C = 64;             // scan chunks; L = 64

    // workspace layout (bytes): total ~210 MB
    char* ws = (char*)d_ws;
    ushort* xb   = (ushort*)(ws);                 // 64 MB  bf16 x
    ushort* updb = (ushort*)(ws + 67108864);      // 64 MB  bf16 upd
    ushort* memb = (ushort*)(ws + 134217728);     // 64 MB  bf16 mem_seq
    ushort* Wub  = (ushort*)(ws + 201326592);     // 2 MB
    ushort* Wfb  = (ushort*)(ws + 203423744);     // 2 MB
    float*  Bc   = (float*)(ws + 205520896);      // <=4 MB   B*C*D
    float*  Mn   = (float*)(ws + 209715200);      // <=4 MB   B*C*D
    float*  Ac   = (float*)(ws + 213909504);      // B*C floats

    const int nx = B * S * D;
    cvt_f32_bf16<<<nx / 1024, 256, 0, stream>>>(x, xb, nx);
    cvt_w2<<<(2 * D * D) / 1024, 256, 0, stream>>>(Wu, Wf, Wub, Wfb, D * D);

    dim3 g1((M / 128) * (D / 128));  // 2048 blocks
    gemm_bt<true><<<g1, 256, 0, stream>>>(xb, Wub, bu, (void*)updb, M, D, D);

    scan_partial<<<B * C, 256, 0, stream>>>(updb, mask, dp, Bc, Ac, S, D, C);
    scan_prefix<<<(B * D) / 256, 256, 0, stream>>>(Ac, Bc, Mn, D, C);
    scan_final<<<B * C, 256, 0, stream>>>(updb, mask, dp, Mn, memb, S, D, C);

    gemm_bt<false><<<g1, 256, 0, stream>>>(memb, Wfb, bfv, d_out, M, D, D);
}

// Round 3
// 448.734 us; speedup vs baseline: 1.1353x; 1.0742x over previous
//
#include <hip/hip_runtime.h>
#include <hip/hip_bf16.h>
#include <math.h>

// Problem dims (fixed by the reference)
#define PB 8
#define PS 4096
#define PD 1024

typedef __attribute__((ext_vector_type(8))) short bf16x8;
typedef __attribute__((ext_vector_type(4))) float f32x4;

__device__ __forceinline__ ushort f2b(float f) {
    // round-to-nearest-even f32 -> bf16
    unsigned u = __float_as_uint(f);
    unsigned r = (u + 0x7FFFu + ((u >> 16) & 1u)) >> 16;
    return (ushort)r;
}
__device__ __forceinline__ float b2f(ushort h) {
    return __uint_as_float(((unsigned)h) << 16);
}

__device__ __forceinline__ void gl2lds16(const void* g, void* l) {
    // async global->LDS, 16B/lane; LDS dest is wave-uniform base + lane*16
    __builtin_amdgcn_global_load_lds(
        (const __attribute__((address_space(1))) void*)g,
        (__attribute__((address_space(3))) void*)l, 16, 0, 0);
}

__global__ __launch_bounds__(256) void cvt_f32_bf16(const float* __restrict__ in,
                                                    ushort* __restrict__ out, int n) {
    int i = (blockIdx.x * 256 + threadIdx.x) * 4;
    if (i + 3 < n) {
        float4 v = *(const float4*)(in + i);
        ushort4 o;
        o.x = f2b(v.x); o.y = f2b(v.y); o.z = f2b(v.z); o.w = f2b(v.w);
        *(ushort4*)(out + i) = o;
    }
}

// both weight matrices in one dispatch
__global__ __launch_bounds__(256) void cvt_w2(const float* __restrict__ Wu,
                                              const float* __restrict__ Wf,
                                              ushort* __restrict__ Wub,
                                              ushort* __restrict__ Wfb, int n) {
    int i = (blockIdx.x * 256 + threadIdx.x) * 4;
    const float* in = (i < n) ? Wu : Wf;
    ushort* out = (i < n) ? Wub : Wfb;
    int j = (i < n) ? i : i - n;
    float4 v = *(const float4*)(in + j);
    ushort4 o;
    o.x = f2b(v.x); o.y = f2b(v.y); o.z = f2b(v.z); o.w = f2b(v.w);
    *(ushort4*)(out + j) = o;
}

// C = A (MxK, row-major bf16) * Bm^T (Bm is NxK row-major bf16) + bias
// 128x128 block tile, BK=64 (two MFMA phases per staged tile -> 16 barriers for K=1024),
// 256 threads = 4 waves, each wave 64x64 (4x4 MFMA tiles).
// LDS rows are 64 elems (128 B); row stride is 0 mod 32 banks, so granules are
// XOR-swizzled: slot granule g of row r holds logical granule g^(r&7).
// Swizzle applied on the GLOBAL address side of the DMA (LDS side must stay linear).
template <bool OUT_BF16>
__global__ __launch_bounds__(256) void gemm_bt(const ushort* __restrict__ A,
                                               const ushort* __restrict__ Bm,
                                               const float* __restrict__ bias,
                                               void* __restrict__ C,
                                               int M, int N, int K) {
    __shared__ ushort As[128 * 64];   // 16 KB, unpadded (required by global_load_lds)
    __shared__ ushort Bs[128 * 64];

    const int tid = threadIdx.x;
    const int lane = tid & 63;
    const int wave = tid >> 6;
    const int nbn = N >> 7;                    // 8
    // XCD-aware mapping: XCD = blockIdx % 8. Each XCD owns M/8 consecutive bm
    // values; bn varies fastest -> A tile reused 8 consecutive steps from that
    // XCD's L2; whole B (2 MB) stays L2-resident.
    const int xcd = blockIdx.x & 7;
    const int g = blockIdx.x >> 3;
    const int bm = xcd * ((M >> 7) >> 3) + g / nbn;
    const int bn = g % nbn;
    const int wm = wave >> 1, wn = wave & 1;
    const int l15 = lane & 15, quad = lane >> 4;

    // staging: per issue-line, wave w covers rows band*32 + w*8 + (lane>>3),
    // slot granule lane&7. Fetch logical granule (lane&7)^((lane>>3)&7).
    const int srow = wave * 8 + (lane >> 3);
    const int sgx = ((lane & 7) ^ ((lane >> 3) & 7)) * 8;
    const ushort* Ag = A + (size_t)(bm * 128 + srow) * K + sgx;
    const ushort* Bg = Bm + (size_t)(bn * 128 + srow) * K + sgx;
    ushort* Asw = As + wave * 8 * 64;   // wave-uniform LDS base
    ushort* Bsw = Bs + wave * 8 * 64;

    f32x4 acc[4][4];
#pragma unroll
    for (int i = 0; i < 4; ++i)
#pragma unroll
        for (int j = 0; j < 4; ++j) acc[i][j] = (f32x4){0.f, 0.f, 0.f, 0.f};

    const int rsw = l15 & 7;   // row&7 for fragment rows

    for (int k0 = 0; k0 < K; k0 += 64) {
        __syncthreads();
#pragma unroll
        for (int b = 0; b < 4; ++b) {
            gl2lds16(Ag + k0 + (size_t)(b * 32) * K, Asw + b * 32 * 64);
            gl2lds16(Bg + k0 + (size_t)(b * 32) * K, Bsw + b * 32 * 64);
        }
        __syncthreads();

#pragma unroll
        for (int p = 0; p < 2; ++p) {
            // logical k-granule = p*4 + quad; slot = logical ^ (row&7)
            const int aoff = ((p * 4 + quad) ^ rsw) * 8;
            bf16x8 af[4], bfr[4];
#pragma unroll
            for (int i = 0; i < 4; ++i)
                af[i] = *(const bf16x8*)(As + (wm * 64 + i * 16 + l15) * 64 + aoff);
#pragma unroll
            for (int j = 0; j < 4; ++j)
                bfr[j] = *(const bf16x8*)(Bs + (wn * 64 + j * 16 + l15) * 64 + aoff);
#pragma unroll
            for (int i = 0; i < 4; ++i)
#pragma unroll
                for (int j = 0; j < 4; ++j)
                    acc[i][j] = __builtin_amdgcn_mfma_f32_16x16x32_bf16(af[i], bfr[j], acc[i][j], 0, 0, 0);
        }
    }

    // epilogue: C/D layout col=lane&15, row=quad*4+reg  [verified m89/m91]
    const int gm0 = bm * 128 + wm * 64;
    const int gn0 = bn * 128 + wn * 64;
    float bv[4];
#pragma unroll
    for (int j = 0; j < 4; ++j) bv[j] = bias[gn0 + j * 16 + l15];
#pragma unroll
    for (int i = 0; i < 4; ++i) {
#pragma unroll
        for (int j = 0; j < 4; ++j) {
            const int col = gn0 + j * 16 + l15;
#pragma unroll
            for (int r = 0; r < 4; ++r) {
                const int row = gm0 + i * 16 + quad * 4 + r;
                float v = acc[i][j][r] + bv[j];
                if (OUT_BF16)
                    ((ushort*)C)[(size_t)row * N + col] = f2b(v);
                else
                    ((float*)C)[(size_t)row * N + col] = v;
            }
        }
    }
}

// Pass A: per (b, chunk) compute affine (A_c scalar, B_c vector of D)
// 4-step batched loads so 4+ ushort4 loads are in flight per wave.
__global__ __launch_bounds__(256) void scan_partial(const ushort* __restrict__ upd,
                                                    const float* __restrict__ mask,
                                                    const float* __restrict__ dp,
                                                    float* __restrict__ Bc,
                                                    float* __restrict__ Ac,
                                                    int S, int D, int C) {
    const int c = blockIdx.x % C;
    const int b = blockIdx.x / C;
    const int L = S / C;
    const int d0 = threadIdx.x * 4;
    const float decay = 1.f / (1.f + expf(-dp[0]));
    const ushort* up = upd + ((size_t)b * S + (size_t)c * L) * D + d0;
    const float* mp = mask + (size_t)b * S + (size_t)c * L;
    float aA = 1.f;
    float b0 = 0.f, b1 = 0.f, b2 = 0.f, b3 = 0.f;
    for (int s0 = 0; s0 < L; s0 += 4) {
        float4 mv = *(const float4*)(mp + s0);
        ushort4 u0 = *(const ushort4*)(up + (size_t)(s0 + 0) * D);
        ushort4 u1 = *(const ushort4*)(up + (size_t)(s0 + 1) * D);
        ushort4 u2 = *(const ushort4*)(up + (size_t)(s0 + 2) * D);
        ushort4 u3 = *(const ushort4*)(up + (size_t)(s0 + 3) * D);
        float m, a;
        m = mv.x; a = m * decay + (1.f - m); aA *= a;
        b0 = a * b0 + m * b2f(u0.x); b1 = a * b1 + m * b2f(u0.y);
        b2 = a * b2 + m * b2f(u0.z); b3 = a * b3 + m * b2f(u0.w);
        m = mv.y; a = m * decay + (1.f - m); aA *= a;
        b0 = a * b0 + m * b2f(u1.x); b1 = a * b1 + m * b2f(u1.y);
        b2 = a * b2 + m * b2f(u1.z); b3 = a * b3 + m * b2f(u1.w);
        m = mv.z; a = m * decay + (1.f - m); aA *= a;
        b0 = a * b0 + m * b2f(u2.x); b1 = a * b1 + m * b2f(u2.y);
        b2 = a * b2 + m * b2f(u2.z); b3 = a * b3 + m * b2f(u2.w);
        m = mv.w; a = m * decay + (1.f - m); aA *= a;
        b0 = a * b0 + m * b2f(u3.x); b1 = a * b1 + m * b2f(u3.y);
        b2 = a * b2 + m * b2f(u3.z); b3 = a * b3 + m * b2f(u3.w);
    }
    *(float4*)(Bc + (size_t)blockIdx.x * D + d0) = make_float4(b0, b1, b2, b3);
    if (threadIdx.x == 0) Ac[blockIdx.x] = aA;
}

// Pass B: serial prefix over C chunks per (b,d) chain; writes incoming state per chunk.
// Unrolled x4 with independent Bc loads prefetched ahead of the dependent chain.
__global__ __launch_bounds__(256) void scan_prefix(const float* __restrict__ Ac,
                                                   const float* __restrict__ Bc,
                                                   float* __restrict__ Mn, int D, int C) {
    int gid = blockIdx.x * 256 + threadIdx.x;  // over B*D
    int b = gid / D;
    int d = gid - b * D;
    float mem = 0.f;
    for (int c = 0; c < C; c += 4) {
        float4 av = *(const float4*)(Ac + b * C + c);
        size_t i0 = ((size_t)(b * C + c)) * D + d;
        float q0 = Bc[i0];
        float q1 = Bc[i0 + D];
        float q2 = Bc[i0 + 2 * (size_t)D];
        float q3 = Bc[i0 + 3 * (size_t)D];
        Mn[i0] = mem;                    mem = av.x * mem + q0;
        Mn[i0 + D] = mem;                mem = av.y * mem + q1;
        Mn[i0 + 2 * (size_t)D] = mem;    mem = av.z * mem + q2;
        Mn[i0 + 3 * (size_t)D] = mem;    mem = av.w * mem + q3;
    }
}

// Pass C: replay each chunk from its incoming state, write mem_seq (bf16)
__global__ __launch_bounds__(256) void scan_final(const ushort* __restrict__ upd,
                                                  const float* __restrict__ mask,
                                                  const float* __restrict__ dp,
                                                  const float* __restrict__ Mn,
                                                  ushort* __restrict__ ms,
                                                  int S, int D, int C) {
    const int c = blockIdx.x % C;
    const int b = blockIdx.x / C;
    const int L = S / C;
    const int d0 = threadIdx.x * 4;
    const float decay = 1.f / (1.f + expf(-dp[0]));
    const ushort* up = upd + ((size_t)b * S + (size_t)c * L) * D + d0;
    ushort* op = ms + ((size_t)b * S + (size_t)c * L) * D + d0;
    const float* mp = mask + (size_t)b * S + (size_t)c * L;
    float4 m0 = *(const float4*)(Mn + (size_t)blockIdx.x * D + d0);
    float v0 = m0.x, v1 = m0.y, v2 = m0.z, v3 = m0.w;
    for (int s0 = 0; s0 < L; s0 += 4) {
        float4 mv = *(const float4*)(mp + s0);
        ushort4 u0 = *(const ushort4*)(up + (size_t)(s0 + 0) * D);
        ushort4 u1 = *(const ushort4*)(up + (size_t)(s0 + 1) * D);
        ushort4 u2 = *(const ushort4*)(up + (size_t)(s0 + 2) * D);
        ushort4 u3 = *(const ushort4*)(up + (size_t)(s0 + 3) * D);
        float m, a;
        ushort4 o;
        m = mv.x; a = m * decay + (1.f - m);
        v0 = a * v0 + m * b2f(u0.x); v1 = a * v1 + m * b2f(u0.y);
        v2 = a * v2 + m * b2f(u0.z); v3 = a * v3 + m * b2f(u0.w);
        o.x = f2b(v0); o.y = f2b(v1); o.z = f2b(v2); o.w = f2b(v3);
        *(ushort4*)(op + (size_t)(s0 + 0) * D) = o;
        m = mv.y; a = m * decay + (1.f - m);
        v0 = a * v0 + m * b2f(u1.x); v1 = a * v1 + m * b2f(u1.y);
        v2 = a * v2 + m * b2f(u1.z); v3 = a * v3 + m * b2f(u1.w);
        o.x = f2b(v0); o.y = f2b(v1); o.z = f2b(v2); o.w = f2b(v3);
        *(ushort4*)(op + (size_t)(s0 + 1) * D) = o;
        m = mv.z; a = m * decay + (1.f - m);
        v0 = a * v0 + m * b2f(u2.x); v1 = a * v1 + m * b2f(u2.y);
        v2 = a * v2 + m * b2f(u2.z); v3 = a * v3 + m * b2f(u2.w);
        o.x = f2b(v0); o.y = f2b(v1); o.z = f2b(v2); o.w = f2b(v3);
        *(ushort4*)(op + (size_t)(s0 + 2) * D) = o;
        m = mv.w; a = m * decay + (1.f - m);
        v0 = a * v0 + m * b2f(u3.x); v1 = a * v1 + m * b2f(u3.y);
        v2 = a * v2 + m * b2f(u3.z); v3 = a * v3 + m * b2f(u3.w);
        o.x = f2b(v0); o.y = f2b(v1); o.z = f2b(v2); o.w = f2b(v3);
        *(ushort4*)(op + (size_t)(s0 + 3) * D) = o;
    }
}

extern "C" void kernel_launch(void* const* d_in, const int* in_sizes, int n_in,
                              void* d_out, int out_size, void* d_ws, size_t ws_size,
                              hipStream_t stream) {
    const float* x    = (const float*)d_in[0];
    const float* mask = (const float*)d_in[1];
    const float* Wu   = (const float*)d_in[2];
    const float* bu   = (const float*)d_in[3];
    const float* Wf   = (const float*)d_in[4];
    const float* bfv  = (const float*)d_in[5];
    const float* dp   = (const float*)d_in[6];

    const int B = PB, S = PS, D = PD;
    const int M = B * S;          // 32768
    const int C = 128;            // scan chunks; L = 32

    // workspace layout (bytes): total ~204 MB
    char* ws = (char*)d_ws;
    ushort* xb   = (ushort*)(ws);                 // 64 MB  bf16 x
    ushort* updb = (ushort*)(ws + 67108864);      // 64 MB  bf16 upd
    ushort* memb = (ushort*)(ws + 134217728);     // 64 MB  bf16 mem_seq
    ushort* Wub  = (ushort*)(ws + 201326592);     // 2 MB
    ushort* Wfb  = (ushort*)(ws + 203423744);     // 2 MB
    float*  Bc   = (float*)(ws + 205520896);      // 4 MB   B*C*D
    float*  Mn   = (float*)(ws + 209715200);      // 4 MB   B*C*D
    float*  Ac   = (float*)(ws + 213909504);      // 4 KB   B*C

    const int nx = B * S * D;
    cvt_f32_bf16<<<nx / 1024, 256, 0, stream>>>(x, xb, nx);
    cvt_w2<<<(2 * D * D) / 1024, 256, 0, stream>>>(Wu, Wf, Wub, Wfb, D * D);

    dim3 g1((M / 128) * (D / 128));  // 2048 blocks
    gemm_bt<true><<<g1, 256, 0, stream>>>(xb, Wub, bu, (void*)updb, M, D, D);

    scan_partial<<<B * C, 256, 0, stream>>>(updb, mask, dp, Bc, Ac, S, D, C);
    scan_prefix<<<(B * D) / 256, 256, 0, stream>>>(Ac, Bc, Mn, D, C);
    scan_final<<<B * C, 256, 0, stream>>>(updb, mask, dp, Mn, memb, S, D, C);

    gemm_bt<false><<<g1, 256, 0, stream>>>(memb, Wfb, bfv, d_out, M, D, D);
}